// Round 4
// baseline (705.186 us; speedup 1.0000x reference)
//
#include <hip/hip_runtime.h>
#include <math.h>

#define NROWS 65536
#define DDIM  256
#define KCODES 1024
#define CHUNK 64                         // codes per pack chunk
#define NCHUNK (KCODES / CHUNK)          // 16
#define KSTEPS 17                        // 16 real K-steps + 1 enorm step
#define PLANE_BYTES (KSTEPS * 2 * CHUNK * 16)   // 34816
#define CHUNK_BYTES (2 * PLANE_BYTES)           // 69632 (hi+lo planes)
#define NSETS 8                          // code-sets (128 codes each)
#define ROWGROUPS 32                     // row groups of 2048
#define SET_BYTES (2 * CHUNK_BYTES)      // 139264 B LDS per block

typedef _Float16 half8 __attribute__((ext_vector_type(8)));
typedef float    f32x16 __attribute__((ext_vector_type(16)));

// ws layout (bytes):
//   [0,       262144)  idx       int32[65536]
//   [266240,  270336)  counts    int32[1024]
//   [270336,  532480)  partials  f32[65536]   (loss)
// out-region scratch (inside encodings, consumed before epilogue overwrites):
//   pack  = out + 16777220          (1,114,112 B, 16B-aligned)
//   pbest = out + 17055748          f32[8][65536]
//   pidx  = (int*)(out + 17580036)  i32[8][65536]
#define PACK_F   16777220
#define PBEST_F  17055748
#define PIDX_F   17580036

// ---------------- prep: pack emb into fragment-ready f16 hi/lo planes ----------------
__global__ __launch_bounds__(256) void pack_emb_kernel(const float* __restrict__ emb,
                                                       char* __restrict__ pack) {
    int tid  = blockIdx.x * 256 + threadIdx.x;   // 32768 threads
    int code = tid >> 5;                          // 0..1023
    int g    = tid & 31;                          // 8-dim group: d0 = g*8
    int ks = g >> 1, kh = g & 1;
    int c = code >> 6, ci = code & 63;
    const float* src = emb + (size_t)code * DDIM + g * 8;
    half8 hi, lo;
#pragma unroll
    for (int j = 0; j < 8; ++j) {
        float v = src[j];
        _Float16 h = (_Float16)v;
        hi[j] = h;
        lo[j] = (_Float16)(v - (float)h);
    }
    size_t off = (size_t)c * CHUNK_BYTES + (size_t)ks * 2048 + (size_t)kh * 1024 + (size_t)ci * 16;
    *(half8*)(pack + off) = hi;
    *(half8*)(pack + off + PLANE_BYTES) = lo;
}

// enorm -> ks=16 slots as 3-term f16 split of -||e||^2/2; also zero counts
__global__ __launch_bounds__(256) void norm_emb_kernel(const float* __restrict__ emb,
                                                       char* __restrict__ pack,
                                                       int* __restrict__ counts) {
    int w = threadIdx.x >> 6, lane = threadIdx.x & 63;
    int code = blockIdx.x * 4 + w;                // grid 256 -> 1024 codes
    float4 v = *(const float4*)(emb + (size_t)code * DDIM + lane * 4);
    float s = v.x * v.x + v.y * v.y + v.z * v.z + v.w * v.w;
    for (int off = 32; off; off >>= 1) s += __shfl_down(s, off, 64);
    s = __shfl(s, 0, 64);
    int c = code >> 6, ci = code & 63;
    size_t base = (size_t)c * CHUNK_BYTES + (size_t)16 * 2048 + (size_t)ci * 16;
    if (lane < 4) {
        half8 val = (half8)(_Float16)0.0f;
        if (lane == 0) {
            float xv = -0.5f * s;
            _Float16 t1 = (_Float16)xv; float r = xv - (float)t1;
            _Float16 t2 = (_Float16)r;  r -= (float)t2;
            _Float16 t3 = (_Float16)r;
            val[0] = t1; val[1] = t2; val[2] = t3;
        }
        size_t off = base + (size_t)(lane & 1) * 1024 + (size_t)(lane >> 1) * PLANE_BYTES;
        *(half8*)(pack + off) = val;
    }
    if (blockIdx.x == 0)
        for (int i = threadIdx.x; i < KCODES; i += 256) counts[i] = 0;
}

// ---------------- argmin: codes LDS-resident, rows streamed, no loop barriers ----------------
__global__ __launch_bounds__(512, 2) void argmin_res(const float* __restrict__ x,
                                                     const char* __restrict__ pack,
                                                     float* __restrict__ pbest,
                                                     int* __restrict__ pidx) {
    extern __shared__ char smem[];     // 139264 B = 2 chunks (128 codes, hi+lo)
    const int tid  = threadIdx.x;
    const int lane = tid & 63;
    const int w    = __builtin_amdgcn_readfirstlane(tid >> 6);   // 0..7
    const int kh   = lane >> 5;
    const int l31  = lane & 31;
    const int s    = blockIdx.x & 7;           // code-set: codes [s*128, s*128+128)
    const int g    = blockIdx.x >> 3;          // row group: rows [g*2048, +2048)

    // one-shot DMA of this set's 2 pack chunks into LDS
    const char* src = pack + (size_t)(2 * s) * CHUNK_BYTES;
    for (int i = w; i < SET_BYTES / 1024; i += 8)
        __builtin_amdgcn_global_load_lds(
            (const __attribute__((address_space(1))) void*)(src + i * 1024 + lane * 16),
            (__attribute__((address_space(3))) void*)(smem + i * 1024), 16, 0, 0);
    __syncthreads();   // only barrier in the kernel

    const int rbase = 4 * kh;

    for (int pass = 0; pass < 8; ++pass) {
        const int row = g * 2048 + pass * 256 + w * 32 + l31;

        // B-frags: this row's f32 -> f16 hi/lo split (kh half). 136 VGPR.
        half8 bh[KSTEPS], bl[KSTEPS];
#pragma unroll
        for (int ks = 0; ks < 16; ++ks) {
            const float* p = x + (size_t)row * DDIM + ks * 16 + kh * 8;
            float4 v0 = *(const float4*)p;
            float4 v1 = *(const float4*)(p + 4);
            float vv[8] = {v0.x, v0.y, v0.z, v0.w, v1.x, v1.y, v1.z, v1.w};
#pragma unroll
            for (int j = 0; j < 8; ++j) {
                _Float16 h = (_Float16)vv[j];
                bh[ks][j] = h;
                bl[ks][j] = (_Float16)(vv[j] - (float)h);
            }
        }
        {
            half8 z = (half8)(_Float16)0.0f;
            bh[16] = z; bl[16] = z;
            if (kh == 0) {
                bh[16][0] = (_Float16)1.0f;
                bh[16][1] = (_Float16)1.0f;
                bh[16][2] = (_Float16)1.0f;
            }
        }

        float bestv = -3.4e38f;
        int   besti = 0;

#pragma unroll
        for (int tp = 0; tp < 2; ++tp) {          // tile-pairs: codes tp*64 .. tp*64+63
            const char* cb = smem + tp * CHUNK_BYTES;
            f32x16 acc0 = (f32x16)0.0f;
            f32x16 acc1 = (f32x16)0.0f;
#pragma unroll
            for (int ks = 0; ks < KSTEPS; ++ks) {
                const char* base = cb + ks * 2048 + kh * 1024;
                half8 ah0 = *(const half8*)(base + l31 * 16);
                half8 ah1 = *(const half8*)(base + 512 + l31 * 16);
                half8 al0 = *(const half8*)(base + PLANE_BYTES + l31 * 16);
                half8 al1 = *(const half8*)(base + PLANE_BYTES + 512 + l31 * 16);
                acc0 = __builtin_amdgcn_mfma_f32_32x32x16_f16(ah0, bh[ks], acc0, 0, 0, 0);
                acc1 = __builtin_amdgcn_mfma_f32_32x32x16_f16(ah1, bh[ks], acc1, 0, 0, 0);
                acc0 = __builtin_amdgcn_mfma_f32_32x32x16_f16(ah0, bl[ks], acc0, 0, 0, 0);
                acc1 = __builtin_amdgcn_mfma_f32_32x32x16_f16(ah1, bl[ks], acc1, 0, 0, 0);
                acc0 = __builtin_amdgcn_mfma_f32_32x32x16_f16(al0, bh[ks], acc0, 0, 0, 0);
                acc1 = __builtin_amdgcn_mfma_f32_32x32x16_f16(al1, bh[ks], acc1, 0, 0, 0);
            }
            int cb0 = s * 128 + tp * 64;
#pragma unroll
            for (int r = 0; r < 16; ++r) {
                int co = cb0 + (r & 3) + 8 * (r >> 2) + rbase;   // verified C-layout (m74/m101)
                float v0 = acc0[r];
                if (v0 > bestv || (v0 == bestv && co < besti)) { bestv = v0; besti = co; }
                float v1 = acc1[r];
                int co1 = co + 32;
                if (v1 > bestv || (v1 == bestv && co1 < besti)) { bestv = v1; besti = co1; }
            }
        }

        // combine kh partners (same row, disjoint code subsets)
        float pv = __shfl_xor(bestv, 32, 64);
        int   pi = __shfl_xor(besti, 32, 64);
        if (pv > bestv || (pv == bestv && pi < besti)) { bestv = pv; besti = pi; }
        if (kh == 0) {
            pbest[s * NROWS + row] = bestv;
            pidx [s * NROWS + row] = besti;
        }
    }
}

// ---------------- merge 8 per-set partials -> final idx ----------------
__global__ __launch_bounds__(256) void merge_kernel(const float* __restrict__ pbest,
                                                    const int* __restrict__ pidx,
                                                    int* __restrict__ outidx) {
    int row = blockIdx.x * 256 + threadIdx.x;
    float bv = pbest[row];
    int   bi = pidx[row];
#pragma unroll
    for (int s = 1; s < NSETS; ++s) {
        float v = pbest[s * NROWS + row];
        int   i = pidx [s * NROWS + row];
        if (v > bv || (v == bv && i < bi)) { bv = v; bi = i; }
    }
    outidx[row] = bi;
}

// ---------------- epilogue + finalize ----------------
__global__ __launch_bounds__(256) void epilogue_kernel(const float* __restrict__ x,
                                                       const float* __restrict__ emb,
                                                       const int* __restrict__ idxbuf,
                                                       float* __restrict__ out,
                                                       float* __restrict__ partials,
                                                       int* __restrict__ counts) {
    int row = blockIdx.x;
    int t   = threadIdx.x;
    int idx = idxbuf[row];

    float q  = emb[(size_t)idx * DDIM + t];
    float xv = x[(size_t)row * DDIM + t];

    float diff = q - xv;
    out[1 + (size_t)row * DDIM + t] = xv + diff;   // match reference rounding

    float* enc = out + 16777218 + (size_t)row * KCODES;
    int base = t * 4;
    float2 z0 = {0.f, 0.f}, z1 = {0.f, 0.f};
    int r = idx - base;
    if (r == 0) z0.x = 1.f;
    else if (r == 1) z0.y = 1.f;
    else if (r == 2) z1.x = 1.f;
    else if (r == 3) z1.y = 1.f;
    *(float2*)(enc + base)     = z0;
    *(float2*)(enc + base + 2) = z1;

    float s = diff * diff;
    for (int off = 32; off; off >>= 1) s += __shfl_down(s, off, 64);
    __shared__ float ps[4];
    if ((t & 63) == 0) ps[t >> 6] = s;
    __syncthreads();
    if (t == 0) partials[row] = ps[0] + ps[1] + ps[2] + ps[3];
    if (t == 1) atomicAdd(&counts[idx], 1);
}

__global__ __launch_bounds__(1024) void finalize_kernel(const float* __restrict__ partials,
                                                        const int* __restrict__ counts,
                                                        float* __restrict__ out) {
    __shared__ double sd[16];
    int t = threadIdx.x;

    double s = 0.0;
    for (int i = t; i < NROWS; i += 1024) s += (double)partials[i];
    for (int off = 32; off; off >>= 1) s += __shfl_down(s, off, 64);
    if ((t & 63) == 0) sd[t >> 6] = s;
    __syncthreads();
    if (t == 0) {
        double tot = 0.0;
        for (int wv = 0; wv < 16; ++wv) tot += sd[wv];
        double mse = tot / ((double)NROWS * (double)DDIM);
        out[0] = (float)(1.25 * mse);
    }
    __syncthreads();

    double h;
    {
        int c = counts[t];
        float p = (float)c / (float)NROWS;
        float term = p * logf(p + 1e-10f);
        h = (double)term;
    }
    for (int off = 32; off; off >>= 1) h += __shfl_down(h, off, 64);
    if ((t & 63) == 0) sd[t >> 6] = h;
    __syncthreads();
    if (t == 0) {
        double tot = 0.0;
        for (int wv = 0; wv < 16; ++wv) tot += sd[wv];
        out[16777217] = expf((float)(-tot));
    }
}

extern "C" void kernel_launch(void* const* d_in, const int* in_sizes, int n_in,
                              void* d_out, int out_size, void* d_ws, size_t ws_size,
                              hipStream_t stream) {
    const float* x   = (const float*)d_in[0];
    const float* emb = (const float*)d_in[1];
    float* out = (float*)d_out;
    char* ws = (char*)d_ws;

    int*   idx      = (int*)ws;
    int*   counts   = (int*)(ws + 266240);
    float* partials = (float*)(ws + 270336);

    char*  pack  = (char*)(out + PACK_F);
    float* pbest = out + PBEST_F;
    int*   pidx  = (int*)(out + PIDX_F);

    hipFuncSetAttribute((const void*)argmin_res,
                        hipFuncAttributeMaxDynamicSharedMemorySize, SET_BYTES);

    pack_emb_kernel<<<128, 256, 0, stream>>>(emb, pack);
    norm_emb_kernel<<<256, 256, 0, stream>>>(emb, pack, counts);
    argmin_res<<<NSETS * ROWGROUPS, 512, SET_BYTES, stream>>>(x, pack, pbest, pidx);
    merge_kernel<<<NROWS / 256, 256, 0, stream>>>(pbest, pidx, idx);
    epilogue_kernel<<<NROWS, 256, 0, stream>>>(x, emb, idx, out, partials, counts);
    finalize_kernel<<<1, 1024, 0, stream>>>(partials, counts, out);
}

// Round 5
// 214.651 us; speedup vs baseline: 3.2853x; 3.2853x over previous
//
#include <hip/hip_runtime.h>
#include <math.h>

#define NROWS 65536
#define DDIM  256
#define KCODES 1024
#define KSTEPS 17                 // 16 real K-steps + 1 enorm step
#define CH_CODES 32               // codes per chunk
#define NCHUNK (KCODES / CH_CODES)          // 32
#define PL_B (KSTEPS * 2 * CH_CODES * 16)   // 17408 plane bytes per chunk
#define CH_B (2 * PL_B)                     // 34816 chunk bytes (hi+lo)
#define ROWS_PER_BLOCK 128

typedef _Float16 half8 __attribute__((ext_vector_type(8)));
typedef float    f32x16 __attribute__((ext_vector_type(16)));

// ws layout (bytes):
//   [0,       262144)  idx       int32[65536]
//   [266240,  270336)  counts    int32[1024]
//   [270336,  532480)  partials  f32[65536]
// pack scratch inside encodings output region (consumed before epilogue overwrites):
//   pack = (char*)(out + 16777220), 32 chunks x 34816 B = 1,114,112 B, 16B-aligned
#define PACK_F 16777220

// ---------------- prep: pack emb into fragment-ready f16 hi/lo planes ----------------
// offset(chunk c, plane, ks, kh, ci, j) = c*CH_B + plane*PL_B + ks*1024 + kh*512 + ci*16 + j*2
__global__ __launch_bounds__(256) void pack_emb_kernel(const float* __restrict__ emb,
                                                       char* __restrict__ pack) {
    int tid  = blockIdx.x * 256 + threadIdx.x;   // 32768 threads
    int code = tid >> 5;                          // 0..1023
    int g    = tid & 31;                          // 8-dim group: d0 = g*8 = ks*16+kh*8
    int ks = g >> 1, kh = g & 1;
    int c = code >> 5, ci = code & 31;
    const float* src = emb + (size_t)code * DDIM + g * 8;
    half8 hi, lo;
#pragma unroll
    for (int j = 0; j < 8; ++j) {
        float v = src[j];
        _Float16 h = (_Float16)v;
        hi[j] = h;
        lo[j] = (_Float16)(v - (float)h);
    }
    size_t off = (size_t)c * CH_B + (size_t)ks * 1024 + (size_t)kh * 512 + (size_t)ci * 16;
    *(half8*)(pack + off) = hi;
    *(half8*)(pack + off + PL_B) = lo;
}

// enorm -> ks=16 slots as 3-term f16 split of -||e||^2/2; also zero counts
__global__ __launch_bounds__(256) void norm_emb_kernel(const float* __restrict__ emb,
                                                       char* __restrict__ pack,
                                                       int* __restrict__ counts) {
    int w = threadIdx.x >> 6, lane = threadIdx.x & 63;
    int code = blockIdx.x * 4 + w;                // grid 256 -> 1024 codes
    float4 v = *(const float4*)(emb + (size_t)code * DDIM + lane * 4);
    float s = v.x * v.x + v.y * v.y + v.z * v.z + v.w * v.w;
    for (int off = 32; off; off >>= 1) s += __shfl_down(s, off, 64);
    s = __shfl(s, 0, 64);
    int c = code >> 5, ci = code & 31;
    size_t base = (size_t)c * CH_B + (size_t)16 * 1024 + (size_t)ci * 16;
    if (lane < 4) {
        half8 val = (half8)(_Float16)0.0f;
        if (lane == 0) {
            float xv = -0.5f * s;
            _Float16 t1 = (_Float16)xv; float r = xv - (float)t1;
            _Float16 t2 = (_Float16)r;  r -= (float)t2;
            _Float16 t3 = (_Float16)r;
            val[0] = t1; val[1] = t2; val[2] = t3;
        }
        // lane0: hi kh0 (data); lane1: hi kh1 = 0; lane2: lo kh0 = 0; lane3: lo kh1 = 0
        size_t off = base + (size_t)(lane & 1) * 512 + (size_t)(lane >> 1) * PL_B;
        *(half8*)(pack + off) = val;
    }
    if (blockIdx.x == 0)
        for (int i = threadIdx.x; i < KCODES; i += 256) counts[i] = 0;
}

// ---------------- argmin: x rows in registers, 32-code chunks streamed, 2 blocks/CU ----------------
__global__ __launch_bounds__(256, 2) void argmin_mfma(const float* __restrict__ x,
                                                      const char* __restrict__ pack,
                                                      int* __restrict__ outidx) {
    extern __shared__ char smem[];     // 2 * 34816 = 69632 B
    const int tid  = threadIdx.x;
    const int lane = tid & 63;
    const int w    = __builtin_amdgcn_readfirstlane(tid >> 6);   // 0..3
    const int kh   = lane >> 5;
    const int l31  = lane & 31;
    const int row  = blockIdx.x * ROWS_PER_BLOCK + w * 32 + l31;

    char* buf0 = smem;
    char* buf1 = smem + CH_B;

    // issue chunk-0 DMA first so it overlaps the B-frag build below
    for (int i = w; i < CH_B / 1024; i += 4)
        __builtin_amdgcn_global_load_lds(
            (const __attribute__((address_space(1))) void*)(pack + i * 1024 + lane * 16),
            (__attribute__((address_space(3))) void*)(buf0 + i * 1024), 16, 0, 0);

    // B-frags: this row's f32 -> f16 hi/lo split (kh half). 136 VGPR.
    half8 bh[KSTEPS], bl[KSTEPS];
#pragma unroll
    for (int ks = 0; ks < 16; ++ks) {
        const float* p = x + (size_t)row * DDIM + ks * 16 + kh * 8;
        float4 v0 = *(const float4*)p;
        float4 v1 = *(const float4*)(p + 4);
        float vv[8] = {v0.x, v0.y, v0.z, v0.w, v1.x, v1.y, v1.z, v1.w};
#pragma unroll
        for (int j = 0; j < 8; ++j) {
            _Float16 h = (_Float16)vv[j];
            bh[ks][j] = h;
            bl[ks][j] = (_Float16)(vv[j] - (float)h);
        }
    }
    {
        half8 z = (half8)(_Float16)0.0f;
        bh[16] = z; bl[16] = z;
        if (kh == 0) {   // enorm coefficients live in k=0..2 of kh0
            bh[16][0] = (_Float16)1.0f;
            bh[16][1] = (_Float16)1.0f;
            bh[16][2] = (_Float16)1.0f;
        }
    }

    __syncthreads();   // chunk 0 resident (drains DMA)

    float bestv = -3.4e38f;
    int   besti = 0;

    for (int c = 0; c < NCHUNK; ++c) {
        char* buf = (c & 1) ? buf1 : buf0;
        if (c + 1 < NCHUNK) {
            const char* src = pack + (size_t)(c + 1) * CH_B;
            char* dst = (c & 1) ? buf0 : buf1;
            for (int i = w; i < CH_B / 1024; i += 4)
                __builtin_amdgcn_global_load_lds(
                    (const __attribute__((address_space(1))) void*)(src + i * 1024 + lane * 16),
                    (__attribute__((address_space(3))) void*)(dst + i * 1024), 16, 0, 0);
        }
        // even/odd ks -> two independent accumulator chains (MFMA latency cover)
        f32x16 accA = (f32x16)0.0f;
        f32x16 accB = (f32x16)0.0f;
#pragma unroll
        for (int ks = 0; ks < KSTEPS; ++ks) {
            const char* base = buf + ks * 1024 + kh * 512;
            half8 ah = *(const half8*)(base + l31 * 16);
            half8 al = *(const half8*)(base + PL_B + l31 * 16);
            if (ks & 1) {
                accB = __builtin_amdgcn_mfma_f32_32x32x16_f16(ah, bh[ks], accB, 0, 0, 0);
                accB = __builtin_amdgcn_mfma_f32_32x32x16_f16(ah, bl[ks], accB, 0, 0, 0);
                accB = __builtin_amdgcn_mfma_f32_32x32x16_f16(al, bh[ks], accB, 0, 0, 0);
            } else {
                accA = __builtin_amdgcn_mfma_f32_32x32x16_f16(ah, bh[ks], accA, 0, 0, 0);
                accA = __builtin_amdgcn_mfma_f32_32x32x16_f16(ah, bl[ks], accA, 0, 0, 0);
                accA = __builtin_amdgcn_mfma_f32_32x32x16_f16(al, bh[ks], accA, 0, 0, 0);
            }
        }
        int cb0 = c * CH_CODES;
#pragma unroll
        for (int r = 0; r < 16; ++r) {
            float v = accA[r] + accB[r];   // score = x.e - ||e||^2/2 (argmax)
            int co = cb0 + (r & 3) + 8 * (r >> 2) + 4 * kh;   // verified C-layout (m74/m101)
            if (v > bestv || (v == bestv && co < besti)) { bestv = v; besti = co; }
        }
        __syncthreads();   // all waves done reading buf before it is re-filled
    }

    // combine kh partners (same row, disjoint code subsets per chunk)
    float pv = __shfl_xor(bestv, 32, 64);
    int   pi = __shfl_xor(besti, 32, 64);
    if (pv > bestv || (pv == bestv && pi < besti)) { bestv = pv; besti = pi; }
    if (kh == 0) outidx[row] = besti;
}

// ---------------- epilogue + finalize ----------------
__global__ __launch_bounds__(256) void epilogue_kernel(const float* __restrict__ x,
                                                       const float* __restrict__ emb,
                                                       const int* __restrict__ idxbuf,
                                                       float* __restrict__ out,
                                                       float* __restrict__ partials,
                                                       int* __restrict__ counts) {
    int row = blockIdx.x;
    int t   = threadIdx.x;
    int idx = idxbuf[row];

    float q  = emb[(size_t)idx * DDIM + t];
    float xv = x[(size_t)row * DDIM + t];

    float diff = q - xv;
    out[1 + (size_t)row * DDIM + t] = xv + diff;   // match reference rounding

    float* enc = out + 16777218 + (size_t)row * KCODES;
    int base = t * 4;
    float2 z0 = {0.f, 0.f}, z1 = {0.f, 0.f};
    int r = idx - base;
    if (r == 0) z0.x = 1.f;
    else if (r == 1) z0.y = 1.f;
    else if (r == 2) z1.x = 1.f;
    else if (r == 3) z1.y = 1.f;
    *(float2*)(enc + base)     = z0;
    *(float2*)(enc + base + 2) = z1;

    float s = diff * diff;
    for (int off = 32; off; off >>= 1) s += __shfl_down(s, off, 64);
    __shared__ float ps[4];
    if ((t & 63) == 0) ps[t >> 6] = s;
    __syncthreads();
    if (t == 0) partials[row] = ps[0] + ps[1] + ps[2] + ps[3];
    if (t == 1) atomicAdd(&counts[idx], 1);
}

__global__ __launch_bounds__(1024) void finalize_kernel(const float* __restrict__ partials,
                                                        const int* __restrict__ counts,
                                                        float* __restrict__ out) {
    __shared__ double sd[16];
    int t = threadIdx.x;

    double s = 0.0;
    for (int i = t; i < NROWS; i += 1024) s += (double)partials[i];
    for (int off = 32; off; off >>= 1) s += __shfl_down(s, off, 64);
    if ((t & 63) == 0) sd[t >> 6] = s;
    __syncthreads();
    if (t == 0) {
        double tot = 0.0;
        for (int wv = 0; wv < 16; ++wv) tot += sd[wv];
        double mse = tot / ((double)NROWS * (double)DDIM);
        out[0] = (float)(1.25 * mse);
    }
    __syncthreads();

    double h;
    {
        int c = counts[t];
        float p = (float)c / (float)NROWS;
        float term = p * logf(p + 1e-10f);
        h = (double)term;
    }
    for (int off = 32; off; off >>= 1) h += __shfl_down(h, off, 64);
    if ((t & 63) == 0) sd[t >> 6] = h;
    __syncthreads();
    if (t == 0) {
        double tot = 0.0;
        for (int wv = 0; wv < 16; ++wv) tot += sd[wv];
        out[16777217] = expf((float)(-tot));
    }
}

extern "C" void kernel_launch(void* const* d_in, const int* in_sizes, int n_in,
                              void* d_out, int out_size, void* d_ws, size_t ws_size,
                              hipStream_t stream) {
    const float* x   = (const float*)d_in[0];
    const float* emb = (const float*)d_in[1];
    float* out = (float*)d_out;
    char* ws = (char*)d_ws;

    int*   idx      = (int*)ws;
    int*   counts   = (int*)(ws + 266240);
    float* partials = (float*)(ws + 270336);

    char* pack = (char*)(out + PACK_F);

    hipFuncSetAttribute((const void*)argmin_mfma,
                        hipFuncAttributeMaxDynamicSharedMemorySize, 2 * CH_B);

    pack_emb_kernel<<<128, 256, 0, stream>>>(emb, pack);
    norm_emb_kernel<<<256, 256, 0, stream>>>(emb, pack, counts);
    argmin_mfma<<<NROWS / ROWS_PER_BLOCK, 256, 2 * CH_B, stream>>>(x, pack, idx);
    epilogue_kernel<<<NROWS, 256, 0, stream>>>(x, emb, idx, out, partials, counts);
    finalize_kernel<<<1, 1024, 0, stream>>>(partials, counts, out);
}

// Round 6
// 206.766 us; speedup vs baseline: 3.4106x; 1.0381x over previous
//
#include <hip/hip_runtime.h>
#include <math.h>

#define NROWS 65536
#define DDIM  256
#define KCODES 1024
#define KSTEPS 16                 // 16 real K-steps; enorm folded at epilogue
#define CH_CODES 32               // codes per chunk
#define NCHUNK (KCODES / CH_CODES)          // 32
#define PL_B (KSTEPS * 2 * CH_CODES * 16)   // 16384 plane bytes per chunk
#define CH_B (2 * PL_B)                     // 32768 chunk bytes (hi+lo)
#define ROWS_PER_BLOCK 128

typedef _Float16 half8 __attribute__((ext_vector_type(8)));
typedef float    f32x16 __attribute__((ext_vector_type(16)));

// ws layout (bytes):
//   [0,       262144)  idx       int32[65536]
//   [262144,  266240)  enorm_pk  f32[1024]  (-0.5*||e||^2, C-layout order)
//   [266240,  270336)  counts    int32[1024]
//   [270336,  532480)  partials  f32[65536]
// pack scratch inside encodings output region (consumed before epilogue overwrites):
//   pack = (char*)(out + 16777220), 32 chunks x 32768 B = 1,048,576 B, 16B-aligned
#define PACK_F 16777220

// ---------------- prep: pack emb into fragment-ready f16 hi/lo planes ----------------
// offset(chunk c, plane, ks, kh, ci, j) = c*CH_B + plane*PL_B + ks*1024 + kh*512 + ci*16 + j*2
__global__ __launch_bounds__(256) void pack_emb_kernel(const float* __restrict__ emb,
                                                       char* __restrict__ pack) {
    int tid  = blockIdx.x * 256 + threadIdx.x;   // 32768 threads
    int code = tid >> 5;                          // 0..1023
    int g    = tid & 31;                          // 8-dim group: d0 = g*8 = ks*16+kh*8
    int ks = g >> 1, kh = g & 1;
    int c = code >> 5, ci = code & 31;
    const float* src = emb + (size_t)code * DDIM + g * 8;
    half8 hi, lo;
#pragma unroll
    for (int j = 0; j < 8; ++j) {
        float v = src[j];
        _Float16 h = (_Float16)v;
        hi[j] = h;
        lo[j] = (_Float16)(v - (float)h);
    }
    size_t off = (size_t)c * CH_B + (size_t)ks * 1024 + (size_t)kh * 512 + (size_t)ci * 16;
    *(half8*)(pack + off) = hi;
    *(half8*)(pack + off + PL_B) = lo;
}

// enorm_pk[c*32 + kh*16 + (w&3) + 4*(w>>3)] = -0.5*||e_code||^2  (w = code&31)
// -> for acc reg r in the argmin kernel, the needed value is enorm_pk[c*32 + kh*16 + r].
__global__ __launch_bounds__(256) void norm_emb_kernel(const float* __restrict__ emb,
                                                       float* __restrict__ enorm_pk,
                                                       int* __restrict__ counts) {
    int w = threadIdx.x >> 6, lane = threadIdx.x & 63;
    int code = blockIdx.x * 4 + w;                // grid 256 -> 1024 codes
    float4 v = *(const float4*)(emb + (size_t)code * DDIM + lane * 4);
    float s = v.x * v.x + v.y * v.y + v.z * v.z + v.w * v.w;
    for (int off = 32; off; off >>= 1) s += __shfl_down(s, off, 64);
    if (lane == 0) {
        int c = code >> 5, wi = code & 31;
        enorm_pk[c * 32 + ((wi >> 2) & 1) * 16 + (wi & 3) + 4 * (wi >> 3)] = -0.5f * s;
    }
    if (blockIdx.x == 0)
        for (int i = threadIdx.x; i < KCODES; i += 256) counts[i] = 0;
}

// ---------------- argmin: x rows in registers, 32-code chunks streamed ----------------
__global__ __launch_bounds__(256, 2) void argmin_mfma(const float* __restrict__ x,
                                                      const char* __restrict__ pack,
                                                      const float* __restrict__ enorm_pk,
                                                      int* __restrict__ outidx) {
    extern __shared__ char smem[];     // 2 * 32768 = 65536 B
    const int tid  = threadIdx.x;
    const int lane = tid & 63;
    const int w    = __builtin_amdgcn_readfirstlane(tid >> 6);   // 0..3
    const int kh   = lane >> 5;
    const int l31  = lane & 31;
    const int row  = blockIdx.x * ROWS_PER_BLOCK + w * 32 + l31;

    char* buf0 = smem;
    char* buf1 = smem + CH_B;

    // issue chunk-0 DMA first so it overlaps the B-frag build below
    for (int i = w; i < CH_B / 1024; i += 4)
        __builtin_amdgcn_global_load_lds(
            (const __attribute__((address_space(1))) void*)(pack + i * 1024 + lane * 16),
            (__attribute__((address_space(3))) void*)(buf0 + i * 1024), 16, 0, 0);

    // B-frags: this row's f32 -> f16 hi/lo split (kh half). 128 VGPR-equivalents.
    half8 bh[KSTEPS], bl[KSTEPS];
#pragma unroll
    for (int ks = 0; ks < KSTEPS; ++ks) {
        const float* p = x + (size_t)row * DDIM + ks * 16 + kh * 8;
        float4 v0 = *(const float4*)p;
        float4 v1 = *(const float4*)(p + 4);
        float vv[8] = {v0.x, v0.y, v0.z, v0.w, v1.x, v1.y, v1.z, v1.w};
#pragma unroll
        for (int j = 0; j < 8; ++j) {
            _Float16 h = (_Float16)vv[j];
            bh[ks][j] = h;
            bl[ks][j] = (_Float16)(vv[j] - (float)h);
        }
    }

    __syncthreads();   // chunk 0 resident (per-wave vmcnt drain + barrier)

    float bestv = -3.4e38f;
    int   besti = 0;

    for (int c = 0; c < NCHUNK; ++c) {
        char* buf = (c & 1) ? buf1 : buf0;
        if (c + 1 < NCHUNK) {
            const char* src = pack + (size_t)(c + 1) * CH_B;
            char* dst = (c & 1) ? buf0 : buf1;
            for (int i = w; i < CH_B / 1024; i += 4)
                __builtin_amdgcn_global_load_lds(
                    (const __attribute__((address_space(1))) void*)(src + i * 1024 + lane * 16),
                    (__attribute__((address_space(3))) void*)(dst + i * 1024), 16, 0, 0);
        }
        // enorm values for this chunk (off the LDS pipe; 4 KB table stays L1-hot)
        const float* enb = enorm_pk + c * 32 + kh * 16;
        float4 e0 = *(const float4*)(enb);
        float4 e1 = *(const float4*)(enb + 4);
        float4 e2 = *(const float4*)(enb + 8);
        float4 e3 = *(const float4*)(enb + 12);
        float er[16] = {e0.x, e0.y, e0.z, e0.w, e1.x, e1.y, e1.z, e1.w,
                        e2.x, e2.y, e2.z, e2.w, e3.x, e3.y, e3.z, e3.w};

        // 3 independent accumulator chains: per ks, the 3 MFMAs have no mutual deps
        f32x16 accA = (f32x16)0.0f;
        f32x16 accB = (f32x16)0.0f;
        f32x16 accC = (f32x16)0.0f;

        half8 ah = *(const half8*)(buf + kh * 512 + l31 * 16);
        half8 al = *(const half8*)(buf + PL_B + kh * 512 + l31 * 16);
#pragma unroll
        for (int ks = 0; ks < KSTEPS; ++ks) {
            half8 ah_n, al_n;
            if (ks + 1 < KSTEPS) {   // software prefetch of next a-frags
                const char* nb = buf + (ks + 1) * 1024 + kh * 512;
                ah_n = *(const half8*)(nb + l31 * 16);
                al_n = *(const half8*)(nb + PL_B + l31 * 16);
            }
            accA = __builtin_amdgcn_mfma_f32_32x32x16_f16(ah, bh[ks], accA, 0, 0, 0);
            accB = __builtin_amdgcn_mfma_f32_32x32x16_f16(ah, bl[ks], accB, 0, 0, 0);
            accC = __builtin_amdgcn_mfma_f32_32x32x16_f16(al, bh[ks], accC, 0, 0, 0);
            ah = ah_n; al = al_n;
        }

        // score = x.e - ||e||^2/2 (argmax). Iteration is ascending-index within this
        // kh half, and chunks ascend -> strict > alone preserves first-index tie-break.
        int cb0 = c * CH_CODES + 4 * kh;
#pragma unroll
        for (int r = 0; r < 16; ++r) {
            float v = accA[r] + accB[r] + accC[r] + er[r];
            int co = cb0 + (r & 3) + 8 * (r >> 2);
            if (v > bestv) { bestv = v; besti = co; }
        }
        __syncthreads();   // all waves done reading buf before it is re-filled
    }

    // combine kh partners (same row, disjoint code subsets per chunk)
    float pv = __shfl_xor(bestv, 32, 64);
    int   pi = __shfl_xor(besti, 32, 64);
    if (pv > bestv || (pv == bestv && pi < besti)) { bestv = pv; besti = pi; }
    if (kh == 0) outidx[row] = besti;
}

// ---------------- epilogue + finalize ----------------
__global__ __launch_bounds__(256) void epilogue_kernel(const float* __restrict__ x,
                                                       const float* __restrict__ emb,
                                                       const int* __restrict__ idxbuf,
                                                       float* __restrict__ out,
                                                       float* __restrict__ partials,
                                                       int* __restrict__ counts) {
    int row = blockIdx.x;
    int t   = threadIdx.x;
    int idx = idxbuf[row];

    float q  = emb[(size_t)idx * DDIM + t];
    float xv = x[(size_t)row * DDIM + t];

    float diff = q - xv;
    out[1 + (size_t)row * DDIM + t] = xv + diff;   // match reference rounding

    float* enc = out + 16777218 + (size_t)row * KCODES;
    int base = t * 4;
    float2 z0 = {0.f, 0.f}, z1 = {0.f, 0.f};
    int r = idx - base;
    if (r == 0) z0.x = 1.f;
    else if (r == 1) z0.y = 1.f;
    else if (r == 2) z1.x = 1.f;
    else if (r == 3) z1.y = 1.f;
    *(float2*)(enc + base)     = z0;
    *(float2*)(enc + base + 2) = z1;

    float s = diff * diff;
    for (int off = 32; off; off >>= 1) s += __shfl_down(s, off, 64);
    __shared__ float ps[4];
    if ((t & 63) == 0) ps[t >> 6] = s;
    __syncthreads();
    if (t == 0) partials[row] = ps[0] + ps[1] + ps[2] + ps[3];
    if (t == 1) atomicAdd(&counts[idx], 1);
}

__global__ __launch_bounds__(1024) void finalize_kernel(const float* __restrict__ partials,
                                                        const int* __restrict__ counts,
                                                        float* __restrict__ out) {
    __shared__ double sd[16];
    int t = threadIdx.x;

    double s = 0.0;
    for (int i = t; i < NROWS; i += 1024) s += (double)partials[i];
    for (int off = 32; off; off >>= 1) s += __shfl_down(s, off, 64);
    if ((t & 63) == 0) sd[t >> 6] = s;
    __syncthreads();
    if (t == 0) {
        double tot = 0.0;
        for (int wv = 0; wv < 16; ++wv) tot += sd[wv];
        double mse = tot / ((double)NROWS * (double)DDIM);
        out[0] = (float)(1.25 * mse);
    }
    __syncthreads();

    double h;
    {
        int c = counts[t];
        float p = (float)c / (float)NROWS;
        float term = p * logf(p + 1e-10f);
        h = (double)term;
    }
    for (int off = 32; off; off >>= 1) h += __shfl_down(h, off, 64);
    if ((t & 63) == 0) sd[t >> 6] = h;
    __syncthreads();
    if (t == 0) {
        double tot = 0.0;
        for (int wv = 0; wv < 16; ++wv) tot += sd[wv];
        out[16777217] = expf((float)(-tot));
    }
}

extern "C" void kernel_launch(void* const* d_in, const int* in_sizes, int n_in,
                              void* d_out, int out_size, void* d_ws, size_t ws_size,
                              hipStream_t stream) {
    const float* x   = (const float*)d_in[0];
    const float* emb = (const float*)d_in[1];
    float* out = (float*)d_out;
    char* ws = (char*)d_ws;

    int*   idx      = (int*)ws;
    float* enorm_pk = (float*)(ws + 262144);
    int*   counts   = (int*)(ws + 266240);
    float* partials = (float*)(ws + 270336);

    char* pack = (char*)(out + PACK_F);

    hipFuncSetAttribute((const void*)argmin_mfma,
                        hipFuncAttributeMaxDynamicSharedMemorySize, 2 * CH_B);

    pack_emb_kernel<<<128, 256, 0, stream>>>(emb, pack);
    norm_emb_kernel<<<256, 256, 0, stream>>>(emb, enorm_pk, counts);
    argmin_mfma<<<NROWS / ROWS_PER_BLOCK, 256, 2 * CH_B, stream>>>(x, pack, enorm_pk, idx);
    epilogue_kernel<<<NROWS, 256, 0, stream>>>(x, emb, idx, out, partials, counts);
    finalize_kernel<<<1, 1024, 0, stream>>>(partials, counts, out);
}